// Round 7
// baseline (665.990 us; speedup 1.0000x reference)
//
#include <hip/hip_runtime.h>
#include <math.h>

#define HID 256

// ---------- edge weight MLP: ew = sigmoid(relu([id_emb|pos_emb] @ W1 + b1) @ W2 + b2)
// also accumulates deg[dst] += ew (float) and cnt[dst]++ (int) — both zeroed first
__global__ void k_edge(const int* __restrict__ eid, const int* __restrict__ epos,
                       const float* __restrict__ id_emb, const float* __restrict__ pos_emb,
                       const float* __restrict__ w1, const float* __restrict__ b1,
                       const float* __restrict__ w2, const float* __restrict__ b2,
                       const int* __restrict__ ei, float* __restrict__ ew,
                       float* __restrict__ deg, int* __restrict__ cnt, int E) {
    __shared__ float sW1[100];
    __shared__ float sB1[10];
    __shared__ float sW2[10];
    __shared__ float sB2;
    int t = threadIdx.x;
    if (t < 100) sW1[t] = w1[t];
    if (t < 10) { sB1[t] = b1[t]; sW2[t] = w2[t]; }
    if (t == 0) sB2 = b2[0];
    __syncthreads();
    int e = blockIdx.x * blockDim.x + t;
    if (e >= E) return;
    int id = eid[e];
    int p  = epos[e];
    const float4* ide = (const float4*)(id_emb + (size_t)id * 8);
    float4 fa = ide[0], fb = ide[1];
    float f[10];
    f[0] = fa.x; f[1] = fa.y; f[2] = fa.z; f[3] = fa.w;
    f[4] = fb.x; f[5] = fb.y; f[6] = fb.z; f[7] = fb.w;
    f[8] = pos_emb[p * 2 + 0];
    f[9] = pos_emb[p * 2 + 1];
    float acc = sB2;
#pragma unroll
    for (int j = 0; j < 10; j++) {
        float h = sB1[j];
#pragma unroll
        for (int i = 0; i < 10; i++) h += f[i] * sW1[i * 10 + j];
        h = fmaxf(h, 0.f);
        acc += h * sW2[j];
    }
    float w = 1.f / (1.f + expf(-acc));
    ew[e] = w;
    int dst = ei[E + e];
    atomicAdd(&deg[dst], w);
    atomicAdd(&cnt[dst], 1);
}

// ---------- dinv = 1/sqrt(deg+1) (in place) AND pack nf rows into float4
__global__ void k_dinv_pack(float* __restrict__ deg, const float* __restrict__ nf,
                            float4* __restrict__ nf4, int N) {
    int i = blockIdx.x * blockDim.x + threadIdx.x;
    if (i >= N) return;
    deg[i] = 1.f / sqrtf(deg[i] + 1.f);
    nf4[i] = make_float4(nf[i * 3 + 0], nf[i * 3 + 1], nf[i * 3 + 2], 0.f);
}

// ---------- exclusive prefix scan of cnt[N] -> row_ptr[N+1] AND cursor[N]
__global__ void k_scan(const int* __restrict__ cnt, int* __restrict__ row_ptr,
                       int* __restrict__ cursor, int N) {
    __shared__ int sums[1024];
    int t = threadIdx.x;
    int per = (N + 1023) / 1024;
    int start = t * per;
    int end = min(start + per, N);
    int s = 0;
    for (int i = start; i < end; i++) s += cnt[i];
    sums[t] = s;
    __syncthreads();
    for (int off = 1; off < 1024; off <<= 1) {
        int v = (t >= off) ? sums[t - off] : 0;
        __syncthreads();
        if (t >= off) sums[t] += v;
        __syncthreads();
    }
    int excl = (t == 0) ? 0 : sums[t - 1];
    for (int i = start; i < end; i++) {
        row_ptr[i] = excl;
        cursor[i] = excl;
        excl += cnt[i];
    }
    if (t == 1023) row_ptr[N] = excl;
}

// ---------- fill CSR: slot = cursor[dst]++; csr[slot] = {src, bitcast(norm)}
__global__ void k_fill(const int* __restrict__ ei, const float* __restrict__ ew,
                       const float* __restrict__ dinv, int* __restrict__ cursor,
                       int2* __restrict__ csr, int E) {
    int e = blockIdx.x * blockDim.x + threadIdx.x;
    if (e >= E) return;
    int src = ei[e];
    int dst = ei[E + e];
    int slot = atomicAdd(&cursor[dst], 1);
    float norm = dinv[src] * ew[e] * dinv[dst];
    csr[slot] = make_int2(src, __float_as_int(norm));
}

// ---------- layer-1 aggregation on RAW packed features, one thread per node
__global__ void k_agg3(const int* __restrict__ row_ptr, const int2* __restrict__ csr,
                       const float4* __restrict__ nf4, const float* __restrict__ dinv,
                       float4* __restrict__ T3, int N) {
    int n = blockIdx.x * blockDim.x + threadIdx.x;
    if (n >= N) return;
    int s = row_ptr[n];
    int e = row_ptr[n + 1];
    float ax = 0.f, ay = 0.f, az = 0.f;
    for (int i = s; i < e; i++) {
        int2 sn = csr[i];
        float w = __int_as_float(sn.y);
        float4 v = nf4[sn.x];
        ax = fmaf(w, v.x, ax);
        ay = fmaf(w, v.y, ay);
        az = fmaf(w, v.z, az);
    }
    float d = dinv[n];
    float dd = d * d;
    float4 v = nf4[n];
    ax = fmaf(dd, v.x, ax);
    ay = fmaf(dd, v.y, ay);
    az = fmaf(dd, v.z, az);
    T3[n] = make_float4(ax, ay, az, 0.f);
}

// ---------- fused layer-2 aggregation: recompute x1 on the fly from T3 (16B/node)
__global__ void k_gatherfused(const int* __restrict__ row_ptr, const int2* __restrict__ csr,
                              const float4* __restrict__ T3, const float* __restrict__ dinv,
                              const float* __restrict__ cw, const float* __restrict__ cb,
                              float* __restrict__ A, int N) {
    int lane = threadIdx.x & 63;
    int wv = threadIdx.x >> 6;
    int n = blockIdx.x * 4 + wv;
    if (n >= N) return;
    const float4 w0 = *(const float4*)(cw + 4 * lane);
    const float4 w1 = *(const float4*)(cw + HID + 4 * lane);
    const float4 w2 = *(const float4*)(cw + 2 * HID + 4 * lane);
    const float4 bv = *(const float4*)(cb + 4 * lane);
    int s = row_ptr[n];
    int e = row_ptr[n + 1];
    float4 acc = make_float4(0.f, 0.f, 0.f, 0.f);
    for (int i = s; i < e; i++) {
        int2 sn = csr[i];
        float w = __int_as_float(sn.y);
        float4 t = T3[sn.x];
        float xx = fmaxf(fmaf(t.x, w0.x, fmaf(t.y, w1.x, fmaf(t.z, w2.x, bv.x))), 0.f);
        float xy = fmaxf(fmaf(t.x, w0.y, fmaf(t.y, w1.y, fmaf(t.z, w2.y, bv.y))), 0.f);
        float xz = fmaxf(fmaf(t.x, w0.z, fmaf(t.y, w1.z, fmaf(t.z, w2.z, bv.z))), 0.f);
        float xw = fmaxf(fmaf(t.x, w0.w, fmaf(t.y, w1.w, fmaf(t.z, w2.w, bv.w))), 0.f);
        acc.x = fmaf(w, xx, acc.x);
        acc.y = fmaf(w, xy, acc.y);
        acc.z = fmaf(w, xz, acc.z);
        acc.w = fmaf(w, xw, acc.w);
    }
    float d = dinv[n];
    float dd = d * d;
    float4 t = T3[n];
    float xx = fmaxf(fmaf(t.x, w0.x, fmaf(t.y, w1.x, fmaf(t.z, w2.x, bv.x))), 0.f);
    float xy = fmaxf(fmaf(t.x, w0.y, fmaf(t.y, w1.y, fmaf(t.z, w2.y, bv.y))), 0.f);
    float xz = fmaxf(fmaf(t.x, w0.z, fmaf(t.y, w1.z, fmaf(t.z, w2.z, bv.z))), 0.f);
    float xw = fmaxf(fmaf(t.x, w0.w, fmaf(t.y, w1.w, fmaf(t.z, w2.w, bv.w))), 0.f);
    acc.x = fmaf(dd, xx, acc.x);
    acc.y = fmaf(dd, xy, acc.y);
    acc.z = fmaf(dd, xz, acc.z);
    acc.w = fmaf(dd, xw, acc.w);
    *(float4*)(A + (size_t)n * HID + lane * 4) = acc;
}

// ================= fused double GEMM, 64-row tile, 8x8 register blocking:
// phase 1: x2 = relu(A @ W2 + b2)
// epilogue: gsum += colsum(x2)
// phase 2: P = x2 @ aw1_top   (x2 round-trips through LDS, never global)
// thread (c5=tid&31, r3=tid>>5): rows 8*r3..+7, cols 8*c5..+7
#define XT_STRIDE 68    // 64 rows + 4 pad
#define X2_STRIDE 260

__global__ __launch_bounds__(256, 2) void k_gemm_fused(
        const float* __restrict__ A, const float* __restrict__ W2,
        const float* __restrict__ b2, const float* __restrict__ aw1,
        float* __restrict__ P, float* __restrict__ gsum, int N) {
    __shared__ __align__(16) float smem[HID * XT_STRIDE];  // 69.6 KB; phase2 overlays x2s[64*260]
    __shared__ __align__(16) float sred[8 * HID];          // 8 KB colsum reduce
    int tid = threadIdx.x;
    int n0 = blockIdx.x * 64;

    // --- stage A tile transposed: smem[col*68 + r], r=row-in-tile
    {
        int r = tid & 63;
        int c16 = tid >> 6;  // 0..3
        int n = n0 + r;
#pragma unroll
        for (int j = 0; j < 16; j++) {
            int c4 = 16 * c16 + j;  // float4-col 0..63
            float4 v = make_float4(0.f, 0.f, 0.f, 0.f);
            if (n < N) v = *(const float4*)(A + (size_t)n * HID + 4 * c4);
            int col = 4 * c4;
            smem[(col + 0) * XT_STRIDE + r] = v.x;
            smem[(col + 1) * XT_STRIDE + r] = v.y;
            smem[(col + 2) * XT_STRIDE + r] = v.z;
            smem[(col + 3) * XT_STRIDE + r] = v.w;
        }
    }
    __syncthreads();

    int c5 = tid & 31;   // cols 8*c5 .. 8*c5+7
    int r3 = tid >> 5;   // rows 8*r3 .. 8*r3+7

    float acc[8][8];
#pragma unroll
    for (int i = 0; i < 8; i++)
#pragma unroll
        for (int c = 0; c < 8; c++) acc[i][c] = 0.f;

    // --- phase 1: x2 = relu(A@W2+b2), k-unroll 4
    {
        const float* Wc = W2 + 8 * c5;
        const float* xb = smem + 8 * r3;
        for (int k0 = 0; k0 < HID; k0 += 4) {
            float4 wA[4], wB[4], xA[4], xB[4];
#pragma unroll
            for (int j = 0; j < 4; j++) {
                const float* wp = Wc + (size_t)(k0 + j) * HID;
                wA[j] = *(const float4*)wp;
                wB[j] = *(const float4*)(wp + 4);
                const float* xp = xb + (k0 + j) * XT_STRIDE;
                xA[j] = *(const float4*)xp;
                xB[j] = *(const float4*)(xp + 4);
            }
#pragma unroll
            for (int j = 0; j < 4; j++) {
                float xr[8], wr[8];
                *(float4*)&xr[0] = xA[j];
                *(float4*)&xr[4] = xB[j];
                *(float4*)&wr[0] = wA[j];
                *(float4*)&wr[4] = wB[j];
#pragma unroll
                for (int i = 0; i < 8; i++)
#pragma unroll
                    for (int c = 0; c < 8; c++)
                        acc[i][c] = fmaf(xr[i], wr[c], acc[i][c]);
            }
        }
    }
    {
        float bb[8];
        *(float4*)&bb[0] = *(const float4*)(b2 + 8 * c5);
        *(float4*)&bb[4] = *(const float4*)(b2 + 8 * c5 + 4);
#pragma unroll
        for (int i = 0; i < 8; i++)
#pragma unroll
            for (int c = 0; c < 8; c++)
                acc[i][c] = fmaxf(acc[i][c] + bb[c], 0.f);
    }
    __syncthreads();  // done reading A^T; smem becomes x2s

    // --- write x2 tile row-major x2s[r*260+c]; per-thread colsum over valid rows
    {
        float cs[8];
#pragma unroll
        for (int c = 0; c < 8; c++) cs[c] = 0.f;
#pragma unroll
        for (int i = 0; i < 8; i++) {
            int r = 8 * r3 + i;
            float* dst = smem + r * X2_STRIDE + 8 * c5;
            *(float4*)dst = *(float4*)&acc[i][0];
            *(float4*)(dst + 4) = *(float4*)&acc[i][4];
            if (n0 + r < N) {
#pragma unroll
                for (int c = 0; c < 8; c++) cs[c] += acc[i][c];
            }
        }
        *(float4*)(sred + r3 * HID + 8 * c5) = *(float4*)&cs[0];
        *(float4*)(sred + r3 * HID + 8 * c5 + 4) = *(float4*)&cs[4];
    }
    __syncthreads();
    {
        float s = 0.f;
#pragma unroll
        for (int g = 0; g < 8; g++) s += sred[g * HID + tid];
        atomicAdd(&gsum[tid], s);
    }

    // --- phase 2: P = x2 @ aw1_top, k-unroll 4 (x2 rows broadcast from LDS)
    float acc2[8][8];
#pragma unroll
    for (int i = 0; i < 8; i++)
#pragma unroll
        for (int c = 0; c < 8; c++) acc2[i][c] = 0.f;
    {
        const float* Wc = aw1 + 8 * c5;
        const float* xb = smem + (8 * r3) * X2_STRIDE;
        for (int k0 = 0; k0 < HID; k0 += 4) {
            float4 wA[4], wB[4];
#pragma unroll
            for (int j = 0; j < 4; j++) {
                const float* wp = Wc + (size_t)(k0 + j) * HID;
                wA[j] = *(const float4*)wp;
                wB[j] = *(const float4*)(wp + 4);
            }
            float4 xr4[8];
#pragma unroll
            for (int i = 0; i < 8; i++)
                xr4[i] = *(const float4*)(xb + i * X2_STRIDE + k0);
#pragma unroll
            for (int j = 0; j < 4; j++) {
                float wr[8];
                *(float4*)&wr[0] = wA[j];
                *(float4*)&wr[4] = wB[j];
#pragma unroll
                for (int i = 0; i < 8; i++) {
                    float xj = (j == 0) ? xr4[i].x : (j == 1) ? xr4[i].y
                             : (j == 2) ? xr4[i].z : xr4[i].w;
#pragma unroll
                    for (int c = 0; c < 8; c++)
                        acc2[i][c] = fmaf(xj, wr[c], acc2[i][c]);
                }
            }
        }
    }
#pragma unroll
    for (int i = 0; i < 8; i++) {
        int n = n0 + 8 * r3 + i;
        if (n < N) {
            float* dst = P + (size_t)n * HID + 8 * c5;
            *(float4*)dst = *(float4*)&acc2[i][0];
            *(float4*)(dst + 4) = *(float4*)&acc2[i][4];
        }
    }
}

// ---------- logits epilogue: out[n] = relu(P[n,:] + gbias) @ aw2 + ab2
__global__ void k_logits(const float* __restrict__ P, const float* __restrict__ gbias,
                         const float* __restrict__ aw2, const float* __restrict__ ab2,
                         float* __restrict__ out, int N) {
    int lane = threadIdx.x & 63;
    int wv = threadIdx.x >> 6;
    int n = blockIdx.x * 4 + wv;
    if (n >= N) return;
    float4 p = *(const float4*)(P + (size_t)n * HID + 4 * lane);
    float4 gb = *(const float4*)(gbias + 4 * lane);
    float4 w2 = *(const float4*)(aw2 + 4 * lane);
    float v = fmaxf(p.x + gb.x, 0.f) * w2.x
            + fmaxf(p.y + gb.y, 0.f) * w2.y
            + fmaxf(p.z + gb.z, 0.f) * w2.z
            + fmaxf(p.w + gb.w, 0.f) * w2.w;
#pragma unroll
    for (int off = 32; off > 0; off >>= 1) v += __shfl_down(v, off, 64);
    if (lane == 0) out[n] = v + ab2[0];
}

// ---------- merged head prep: block 0 -> gbias, block 1 -> critic value
__global__ void k_heads(const float* __restrict__ gsum,
                        const float* __restrict__ aw1, const float* __restrict__ ab1,
                        float* __restrict__ gbias,
                        const float* __restrict__ cw1, const float* __restrict__ cb1,
                        const float* __restrict__ cw2, const float* __restrict__ cb2,
                        const float* __restrict__ cw3, const float* __restrict__ cb3,
                        float* __restrict__ sv_out, float invN) {
    int t = threadIdx.x;  // 512
    if (blockIdx.x == 0) {
        if (t < HID) {
            float s = ab1[t];
            for (int j = 0; j < HID; j++) s += gsum[j] * invN * aw1[(HID + j) * HID + t];
            gbias[t] = s;
        }
        return;
    }
    __shared__ float p[2 * HID];
    __shared__ float c1[2 * HID];
    __shared__ float c2[HID];
    p[t] = gsum[t & (HID - 1)] * invN;
    __syncthreads();
    float s = cb1[t];
    for (int i = 0; i < 2 * HID; i++) s += p[i] * cw1[i * 2 * HID + t];
    c1[t] = fmaxf(s, 0.f);
    __syncthreads();
    if (t < HID) {
        float s2 = cb2[t];
        for (int i = 0; i < 2 * HID; i++) s2 += c1[i] * cw2[i * HID + t];
        c2[t] = fmaxf(s2, 0.f) * cw3[t];
    }
    __syncthreads();
    for (int st = HID / 2; st > 0; st >>= 1) {
        if (t < st) c2[t] += c2[t + st];
        __syncthreads();
    }
    if (t == 0) sv_out[0] = c2[0] + cb3[0];
}

extern "C" void kernel_launch(void* const* d_in, const int* in_sizes, int n_in,
                              void* d_out, int out_size, void* d_ws, size_t ws_size,
                              hipStream_t stream) {
    const float* nf      = (const float*)d_in[0];
    const int*   ei      = (const int*)d_in[1];
    const int*   eid     = (const int*)d_in[2];
    const int*   epos    = (const int*)d_in[3];
    const float* id_emb  = (const float*)d_in[4];
    const float* pos_emb = (const float*)d_in[5];
    const float* ew_w1   = (const float*)d_in[6];
    const float* ew_b1   = (const float*)d_in[7];
    const float* ew_w2   = (const float*)d_in[8];
    const float* ew_b2   = (const float*)d_in[9];
    const float* c1w     = (const float*)d_in[10];
    const float* c1b     = (const float*)d_in[11];
    const float* c2w     = (const float*)d_in[12];
    const float* c2b     = (const float*)d_in[13];
    const float* aw1     = (const float*)d_in[14];
    const float* ab1     = (const float*)d_in[15];
    const float* aw2     = (const float*)d_in[16];
    const float* ab2     = (const float*)d_in[17];
    const float* cw1     = (const float*)d_in[18];
    const float* cb1     = (const float*)d_in[19];
    const float* cw2     = (const float*)d_in[20];
    const float* cb2     = (const float*)d_in[21];
    const float* cw3     = (const float*)d_in[22];
    const float* cb3     = (const float*)d_in[23];

    int N = in_sizes[0] / 3;
    int E = in_sizes[2];
    float invN = 1.f / (float)N;

    char* ws = (char*)d_ws;
    float* A        = (float*)ws;                         ws += (size_t)N * HID * 4;
    float* P        = (float*)ws;                         ws += (size_t)N * HID * 4;
    float* ew       = (float*)ws;                         ws += (size_t)E * 4;
    int2*  csr      = (int2*)ws;                          ws += (size_t)E * 8;
    float* deg      = (float*)ws;                         ws += (size_t)N * 4;
    int*   cnt      = (int*)ws;                           ws += (size_t)N * 4;
    int*   row_ptr  = (int*)ws;                           ws += (size_t)(N + 1) * 4;
    int*   cursor   = (int*)ws;                           ws += (size_t)N * 4;
    float4* T3      = (float4*)ws;                        ws += (size_t)N * 16;
    float4* nf4     = (float4*)ws;                        ws += (size_t)N * 16;
    float* gsum     = (float*)ws;                         ws += HID * 4;
    float* gbias    = (float*)ws;                         ws += HID * 4;

    float* out = (float*)d_out;  // [N] logits + [1] state value

    // --- edge MLP + degree + histogram
    hipMemsetAsync(deg, 0, (size_t)N * sizeof(float), stream);
    hipMemsetAsync(cnt, 0, (size_t)N * sizeof(int), stream);
    hipMemsetAsync(gsum, 0, HID * sizeof(float), stream);
    k_edge<<<(E + 255) / 256, 256, 0, stream>>>(eid, epos, id_emb, pos_emb,
                                                ew_w1, ew_b1, ew_w2, ew_b2, ei, ew, deg, cnt, E);
    k_dinv_pack<<<(N + 255) / 256, 256, 0, stream>>>(deg, nf, nf4, N);

    // --- CSR build
    k_scan<<<1, 1024, 0, stream>>>(cnt, row_ptr, cursor, N);
    k_fill<<<(E + 255) / 256, 256, 0, stream>>>(ei, ew, deg, cursor, csr, E);

    // --- layer 1 aggregate on raw features (16B/node)
    k_agg3<<<(N + 255) / 256, 256, 0, stream>>>(row_ptr, csr, nf4, deg, T3, N);

    // --- layer 2 aggregate with x1 recomputed on the fly
    k_gatherfused<<<(N + 3) / 4, 256, 0, stream>>>(row_ptr, csr, T3, deg, c1w, c1b, A, N);

    // --- fused conv2-GEMM + actor-GEMM (+ colsum); x2 stays on-chip; 64-row tiles
    k_gemm_fused<<<(N + 63) / 64, 256, 0, stream>>>(A, c2w, c2b, aw1, P, gsum, N);

    // --- heads prep: gbias (block 0) + critic value (block 1, writes out[N])
    k_heads<<<2, 2 * HID, 0, stream>>>(gsum, aw1, ab1, gbias,
                                       cw1, cb1, cw2, cb2, cw3, cb3, out + N, invN);

    // --- logits epilogue (writes out[0..N))
    k_logits<<<(N + 3) / 4, 256, 0, stream>>>(P, gbias, aw2, ab2, out, N);
}